// Round 1
// baseline (160.583 us; speedup 1.0000x reference)
//
#include <hip/hip_runtime.h>
#include <math.h>

static constexpr int B_ = 32, M_ = 100, L_ = 30, LQ_ = 30, E_ = 256, V_ = 32000;

// ---------------- Kernel 1: query embedding u0 = sum_l A1[Q[b,l]] * pe_q[l,:] * QM[b,l]
__global__ __launch_bounds__(256) void k_query(const int* __restrict__ trainQ,
                                               const float* __restrict__ trainQM,
                                               const float* __restrict__ A1,
                                               float* __restrict__ u) {
    const int b = blockIdx.x;
    const int e = threadIdx.x;
    const float half_e = (E_ + 1) * 0.5f;
    const float half_j = (LQ_ + 1) * 0.5f;
    const float inv = 1.0f / (float)(E_ * LQ_);
    const float ke = (float)(e + 1) - half_e;
    float acc = 0.f;
    for (int l = 0; l < LQ_; ++l) {
        const int q = trainQ[b * LQ_ + l];
        const float qm = trainQM[b * LQ_ + l];
        const float pe = 1.0f + 4.0f * ke * ((float)(l + 1) - half_j) * inv;
        acc += A1[(size_t)q * E_ + e] * pe * qm;
    }
    u[b * E_ + e] = acc;
}

// ---------------- Kernel 2: story embeddings embA_k[b,m,:] = sum_l A_k[S[b,m,l]] * pe_s[l,:]
// One block per (b,m). Wave w handles table w; 64 lanes cover E via float4.
__global__ __launch_bounds__(256) void k_embed(const int* __restrict__ trainS,
                                               const float* __restrict__ A1,
                                               const float* __restrict__ A2,
                                               const float* __restrict__ A3,
                                               const float* __restrict__ A4,
                                               float* __restrict__ embA) {
    const int bm = blockIdx.x;
    const int tbl = threadIdx.x >> 6;
    const int e0 = (threadIdx.x & 63) * 4;
    const float* __restrict__ A = (tbl == 0) ? A1 : (tbl == 1) ? A2 : (tbl == 2) ? A3 : A4;
    const float half_e = (E_ + 1) * 0.5f;
    const float half_j = (L_ + 1) * 0.5f;
    const float inv = 1.0f / (float)(E_ * L_);
    const float k0 = (float)(e0 + 1) - half_e;
    const float k1 = k0 + 1.f, k2 = k0 + 2.f, k3 = k0 + 3.f;
    float4 acc = make_float4(0.f, 0.f, 0.f, 0.f);
    for (int l = 0; l < L_; ++l) {
        const int idx = trainS[bm * L_ + l];
        const float coef = 4.0f * ((float)(l + 1) - half_j) * inv;
        const float4 a = *reinterpret_cast<const float4*>(A + (size_t)idx * E_ + e0);
        acc.x += a.x * (1.0f + coef * k0);
        acc.y += a.y * (1.0f + coef * k1);
        acc.z += a.z * (1.0f + coef * k2);
        acc.w += a.w * (1.0f + coef * k3);
    }
    *reinterpret_cast<float4*>(embA + (size_t)tbl * (B_ * M_ * E_) + (size_t)bm * E_ + e0) = acc;
}

// ---------------- Kernel 3: three attention hops, one block per batch element.
__global__ __launch_bounds__(256) void k_hops(const float* __restrict__ embA,
                                              const float* __restrict__ trainPM,
                                              float* __restrict__ u) {
    const int b = blockIdx.x;
    const int tid = threadIdx.x;
    const int lane = tid & 63;
    const int wave = tid >> 6;
    __shared__ float u_sh[E_];
    __shared__ float sc[M_];
    __shared__ float p_sh[M_];
    u_sh[tid] = u[b * E_ + tid];
    __syncthreads();
    for (int hop = 0; hop < 3; ++hop) {
        const float* memA = embA + (size_t)hop * (B_ * M_ * E_) + (size_t)b * M_ * E_;
        const float* memC = memA + (size_t)(B_ * M_ * E_);
        // scores[m] = dot(memA[m,:], u) * PM[m]
        for (int m = wave; m < M_; m += 4) {
            const float* row = memA + m * E_;
            float part = 0.f;
#pragma unroll
            for (int j = 0; j < 4; ++j)
                part += row[lane + 64 * j] * u_sh[lane + 64 * j];
#pragma unroll
            for (int off = 32; off > 0; off >>= 1)
                part += __shfl_xor(part, off, 64);
            if (lane == 0) sc[m] = part * trainPM[b * M_ + m];
        }
        __syncthreads();
        // masked softmax over M (wave 0 only)
        if (wave == 0) {
            const float pm0 = (lane < M_) ? trainPM[b * M_ + lane] : 0.f;
            const float pm1 = (lane + 64 < M_) ? trainPM[b * M_ + lane + 64] : 0.f;
            const float x0 = (lane < M_ && pm0 > 0.f) ? sc[lane] : -1e30f;
            const float x1 = (lane + 64 < M_ && pm1 > 0.f) ? sc[lane + 64] : -1e30f;
            float mx = fmaxf(x0, x1);
#pragma unroll
            for (int off = 32; off > 0; off >>= 1)
                mx = fmaxf(mx, __shfl_xor(mx, off, 64));
            const float e0 = (lane < M_) ? expf(x0 - mx) * pm0 : 0.f;
            const float e1 = (lane + 64 < M_) ? expf(x1 - mx) * pm1 : 0.f;
            float ssum = e0 + e1;
#pragma unroll
            for (int off = 32; off > 0; off >>= 1)
                ssum += __shfl_xor(ssum, off, 64);
            const float invs = 1.0f / (ssum + 1e-13f);
            if (lane < M_) p_sh[lane] = e0 * invs;
            if (lane + 64 < M_) p_sh[lane + 64] = e1 * invs;
        }
        __syncthreads();
        // o[e] = sum_m p[m] * memC[m,e];  u += o
        float acc = 0.f;
        const float* crow = memC + tid;
        for (int m = 0; m < M_; ++m)
            acc += p_sh[m] * crow[(size_t)m * E_];
        u_sh[tid] += acc;
        __syncthreads();
    }
    u[b * E_ + tid] = u_sh[tid];
}

// ---------------- Kernel 4: wx = u @ W.T + b; LayerNorm over batch axis; add log(mask)
// 256 threads; 128 v per block; 2 threads per v split E in halves; all 32 batch accs in regs.
__global__ __launch_bounds__(256) void k_output(const float* __restrict__ u,
                                                const float* __restrict__ Wm,
                                                const float* __restrict__ bias,
                                                const float* __restrict__ gamma,
                                                const float* __restrict__ beta,
                                                const float* __restrict__ VM,
                                                float* __restrict__ z) {
    __shared__ float u_sh[B_ * E_];
    __shared__ float part[128 * 33];
    const int tid = threadIdx.x;
    for (int i = tid; i < (B_ * E_) / 4; i += 256)
        reinterpret_cast<float4*>(u_sh)[i] = reinterpret_cast<const float4*>(u)[i];
    __syncthreads();
    const int vl = tid & 127;
    const int eh = tid >> 7;
    const int v = blockIdx.x * 128 + vl;
    float acc[B_];
#pragma unroll
    for (int b = 0; b < B_; ++b) acc[b] = 0.f;
    const float4* wrow = reinterpret_cast<const float4*>(Wm + (size_t)v * E_ + eh * 128);
#pragma unroll 2
    for (int i = 0; i < 32; ++i) {
        const float4 w4 = wrow[i];
        const int e = eh * 128 + i * 4;
#pragma unroll
        for (int b = 0; b < B_; ++b) {
            const float4 uu = *reinterpret_cast<const float4*>(u_sh + b * E_ + e);
            acc[b] += w4.x * uu.x + w4.y * uu.y + w4.z * uu.z + w4.w * uu.w;
        }
    }
    if (eh == 1) {
#pragma unroll
        for (int b = 0; b < B_; ++b) part[vl * 33 + b] = acc[b];
    }
    __syncthreads();
    if (eh == 0) {
        float wx[B_];
        const float bv = bias[v];
        float mean = 0.f;
#pragma unroll
        for (int b = 0; b < B_; ++b) {
            wx[b] = acc[b] + part[vl * 33 + b] + bv;
            mean += wx[b];
        }
        mean *= (1.0f / B_);
        float var = 0.f;
#pragma unroll
        for (int b = 0; b < B_; ++b) {
            const float d = wx[b] - mean;
            var += d * d;
        }
        var *= (1.0f / B_);
        const float rstd = rsqrtf(var + 1e-5f);
        const float g = gamma[v], be = beta[v];
#pragma unroll
        for (int b = 0; b < B_; ++b) {
            const float y = g * (wx[b] - mean) * rstd + be;
            z[(size_t)b * V_ + v] = y + logf(VM[(size_t)b * V_ + v] + 1e-13f);
        }
    }
}

// ---------------- Kernel 5: per-row logsumexp over V
__global__ __launch_bounds__(1024) void k_lse(const float* __restrict__ z,
                                              float* __restrict__ lse) {
    const int b = blockIdx.x;
    const int tid = threadIdx.x;
    float m = -1e30f, s = 0.f;
    for (int v = tid; v < V_; v += 1024) {
        const float x = z[(size_t)b * V_ + v];
        if (x > m) { s = s * expf(m - x) + 1.f; m = x; }
        else s += expf(x - m);
    }
#pragma unroll
    for (int off = 32; off > 0; off >>= 1) {
        const float m2 = __shfl_xor(m, off, 64);
        const float s2 = __shfl_xor(s, off, 64);
        const float mm = fmaxf(m, m2);
        s = s * expf(m - mm) + s2 * expf(m2 - mm);
        m = mm;
    }
    __shared__ float ms[16], ss[16];
    const int wave = tid >> 6, lane = tid & 63;
    if (lane == 0) { ms[wave] = m; ss[wave] = s; }
    __syncthreads();
    if (tid == 0) {
        float mm = ms[0];
        for (int w = 1; w < 16; ++w) mm = fmaxf(mm, ms[w]);
        float S = 0.f;
        for (int w = 0; w < 16; ++w) S += ss[w] * expf(ms[w] - mm);
        lse[b] = mm + logf(S);
    }
}

// ---------------- Kernel 6: out = z - lse[b]
__global__ __launch_bounds__(256) void k_final(const float* __restrict__ z,
                                               const float* __restrict__ lse,
                                               float* __restrict__ out) {
    const int blocksPerRow = V_ / 256; // 125
    const int b = blockIdx.x / blocksPerRow;
    const int v = (blockIdx.x % blocksPerRow) * 256 + threadIdx.x;
    out[(size_t)b * V_ + v] = z[(size_t)b * V_ + v] - lse[b];
}

extern "C" void kernel_launch(void* const* d_in, const int* in_sizes, int n_in,
                              void* d_out, int out_size, void* d_ws, size_t ws_size,
                              hipStream_t stream) {
    const int* trainS = (const int*)d_in[0];
    const int* trainQ = (const int*)d_in[1];
    const float* trainVM = (const float*)d_in[2];
    const float* trainPM = (const float*)d_in[3];
    // d_in[4] = trainSM (unused by the forward pass)
    const float* trainQM = (const float*)d_in[5];
    const float* A1 = (const float*)d_in[6];
    const float* A2 = (const float*)d_in[7];
    const float* A3 = (const float*)d_in[8];
    const float* A4 = (const float*)d_in[9];
    const float* Wm = (const float*)d_in[10];
    const float* bias = (const float*)d_in[11];
    const float* gamma = (const float*)d_in[12];
    const float* beta = (const float*)d_in[13];
    float* out = (float*)d_out;

    float* ws = (float*)d_ws;
    float* u = ws;                                   // B*E = 8192
    float* embA = ws + 8192;                         // 4*B*M*E = 3,276,800
    float* z = ws + 8192 + 4 * (B_ * M_ * E_);       // B*V = 1,024,000
    float* lse = z + (size_t)B_ * V_;                // 32

    k_query<<<B_, 256, 0, stream>>>(trainQ, trainQM, A1, u);
    k_embed<<<B_ * M_, 256, 0, stream>>>(trainS, A1, A2, A3, A4, embA);
    k_hops<<<B_, 256, 0, stream>>>(embA, trainPM, u);
    k_output<<<V_ / 128, 256, 0, stream>>>(u, Wm, bias, gamma, beta, trainVM, z);
    k_lse<<<B_, 1024, 0, stream>>>(z, lse);
    k_final<<<B_ * (V_ / 256), 256, 0, stream>>>(z, lse, out);
}

// Round 2
// 123.026 us; speedup vs baseline: 1.3053x; 1.3053x over previous
//
#include <hip/hip_runtime.h>
#include <math.h>

static constexpr int B_ = 32, M_ = 100, L_ = 30, LQ_ = 30, E_ = 256, V_ = 32000;

// ---------------- Kernel 1: story embeddings embA_k[b,m,:] = sum_l A_k[S[b,m,l]] * pe_s[l,:]
// One block per (b,m). Wave w handles table w; 64 lanes cover E via float4.
// MLP fix: preload indices (uniform -> SGPR), gather in chunks of 10 float4s
// into registers before accumulating -> 10+ loads in flight per wave.
__global__ __launch_bounds__(256) void k_embed(const int* __restrict__ trainS,
                                               const float* __restrict__ A1,
                                               const float* __restrict__ A2,
                                               const float* __restrict__ A3,
                                               const float* __restrict__ A4,
                                               float* __restrict__ embA) {
    const int bm = blockIdx.x;
    const int tbl = threadIdx.x >> 6;
    const int e0 = (threadIdx.x & 63) * 4;
    const float* __restrict__ A = (tbl == 0) ? A1 : (tbl == 1) ? A2 : (tbl == 2) ? A3 : A4;
    const float half_e = (E_ + 1) * 0.5f;
    const float half_j = (L_ + 1) * 0.5f;
    const float inv = 1.0f / (float)(E_ * L_);
    const float k0 = (float)(e0 + 1) - half_e;
    const float k1 = k0 + 1.f, k2 = k0 + 2.f, k3 = k0 + 3.f;

    int idx[L_];
#pragma unroll
    for (int l = 0; l < L_; ++l) idx[l] = trainS[bm * L_ + l];  // uniform -> scalar loads

    float4 acc = make_float4(0.f, 0.f, 0.f, 0.f);
#pragma unroll
    for (int c = 0; c < 3; ++c) {
        float4 r[10];
#pragma unroll
        for (int j = 0; j < 10; ++j)
            r[j] = *reinterpret_cast<const float4*>(A + (size_t)idx[c * 10 + j] * E_ + e0);
#pragma unroll
        for (int j = 0; j < 10; ++j) {
            const int l = c * 10 + j;
            const float coef = 4.0f * ((float)(l + 1) - half_j) * inv;
            acc.x += r[j].x * (1.0f + coef * k0);
            acc.y += r[j].y * (1.0f + coef * k1);
            acc.z += r[j].z * (1.0f + coef * k2);
            acc.w += r[j].w * (1.0f + coef * k3);
        }
    }
    *reinterpret_cast<float4*>(embA + (size_t)tbl * (B_ * M_ * E_) + (size_t)bm * E_ + e0) = acc;
}

// ---------------- Kernel 2: query embedding + three attention hops. One 1024-thread block per b.
__global__ __launch_bounds__(1024) void k_hops(const int* __restrict__ trainQ,
                                               const float* __restrict__ trainQM,
                                               const float* __restrict__ A1,
                                               const float* __restrict__ embA,
                                               const float* __restrict__ trainPM,
                                               float* __restrict__ u_out) {
    const int b = blockIdx.x;
    const int tid = threadIdx.x;
    const int lane = tid & 63;
    const int wave = tid >> 6;
    const int g = tid >> 8;     // 0..3
    const int e = tid & 255;
    __shared__ float u_sh[E_];
    __shared__ float sc[M_];
    __shared__ float p_sh[M_];
    __shared__ float osum[4][E_];

    // ---- query embedding: u0[e] = sum_l A1[Q[b,l],e] * pe_q[l,e] * QM[b,l]
    {
        const float half_e = (E_ + 1) * 0.5f;
        const float half_j = (LQ_ + 1) * 0.5f;
        const float inv = 1.0f / (float)(E_ * LQ_);
        const float ke = (float)(e + 1) - half_e;
        const int l0 = g * 8;
        const int ln = (LQ_ - l0 < 8) ? (LQ_ - l0) : 8;  // 8,8,8,6
        int qi[8];
        float qm[8];
#pragma unroll
        for (int j = 0; j < 8; ++j) {
            if (j < ln) {
                qi[j] = trainQ[b * LQ_ + l0 + j];
                qm[j] = trainQM[b * LQ_ + l0 + j];
            } else { qi[j] = 0; qm[j] = 0.f; }
        }
        float r[8];
#pragma unroll
        for (int j = 0; j < 8; ++j)
            r[j] = (j < ln) ? A1[(size_t)qi[j] * E_ + e] : 0.f;
        float part = 0.f;
#pragma unroll
        for (int j = 0; j < 8; ++j) {
            const float pe = 1.0f + 4.0f * ke * ((float)(l0 + j + 1) - half_j) * inv;
            part += r[j] * pe * qm[j];
        }
        osum[g][e] = part;
    }
    __syncthreads();
    if (tid < E_) u_sh[tid] = osum[0][tid] + osum[1][tid] + osum[2][tid] + osum[3][tid];
    __syncthreads();

    for (int hop = 0; hop < 3; ++hop) {
        const float* memA = embA + (size_t)hop * (B_ * M_ * E_) + (size_t)b * M_ * E_;
        const float* memC = memA + (size_t)(B_ * M_ * E_);
        // scores[m] = dot(memA[m,:], u) * PM[m]   (16 waves, strided)
#pragma unroll 2
        for (int m = wave; m < M_; m += 16) {
            const float* row = memA + m * E_;
            float part = 0.f;
#pragma unroll
            for (int j = 0; j < 4; ++j)
                part += row[lane + 64 * j] * u_sh[lane + 64 * j];
#pragma unroll
            for (int off = 32; off > 0; off >>= 1)
                part += __shfl_xor(part, off, 64);
            if (lane == 0) sc[m] = part * trainPM[b * M_ + m];
        }
        __syncthreads();
        // masked softmax over M (wave 0 only)
        if (wave == 0) {
            const float pm0 = (lane < M_) ? trainPM[b * M_ + lane] : 0.f;
            const float pm1 = (lane + 64 < M_) ? trainPM[b * M_ + lane + 64] : 0.f;
            const float x0 = (lane < M_ && pm0 > 0.f) ? sc[lane] : -1e30f;
            const float x1 = (lane + 64 < M_ && pm1 > 0.f) ? sc[lane + 64] : -1e30f;
            float mx = fmaxf(x0, x1);
#pragma unroll
            for (int off = 32; off > 0; off >>= 1)
                mx = fmaxf(mx, __shfl_xor(mx, off, 64));
            const float e0v = (lane < M_) ? expf(x0 - mx) * pm0 : 0.f;
            const float e1v = (lane + 64 < M_) ? expf(x1 - mx) * pm1 : 0.f;
            float ssum = e0v + e1v;
#pragma unroll
            for (int off = 32; off > 0; off >>= 1)
                ssum += __shfl_xor(ssum, off, 64);
            const float invs = 1.0f / (ssum + 1e-13f);
            if (lane < M_) p_sh[lane] = e0v * invs;
            if (lane + 64 < M_) p_sh[lane + 64] = e1v * invs;
        }
        __syncthreads();
        // o[e] = sum_m p[m]*memC[m,e]; 4 groups of 25 m each
        {
            float acc = 0.f;
            const float* crow = memC + e;
            const int m0 = g * 25;
#pragma unroll 5
            for (int mm = 0; mm < 25; ++mm)
                acc += p_sh[m0 + mm] * crow[(size_t)(m0 + mm) * E_];
            osum[g][e] = acc;
        }
        __syncthreads();
        if (tid < E_) u_sh[tid] += osum[0][tid] + osum[1][tid] + osum[2][tid] + osum[3][tid];
        __syncthreads();
    }
    if (tid < E_) u_out[b * E_ + tid] = u_sh[tid];
}

// ---------------- Kernel 3: wx = u @ W.T + b; LayerNorm over batch axis; add log(mask)
// 256 threads; 128 v per block; 2 threads per v split E in halves; 8-deep W preload.
__global__ __launch_bounds__(256) void k_output(const float* __restrict__ u,
                                                const float* __restrict__ Wm,
                                                const float* __restrict__ bias,
                                                const float* __restrict__ gamma,
                                                const float* __restrict__ beta,
                                                const float* __restrict__ VM,
                                                float* __restrict__ z) {
    __shared__ float u_sh[B_ * E_];
    __shared__ float part[128 * 33];
    const int tid = threadIdx.x;
    for (int i = tid; i < (B_ * E_) / 4; i += 256)
        reinterpret_cast<float4*>(u_sh)[i] = reinterpret_cast<const float4*>(u)[i];
    __syncthreads();
    const int vl = tid & 127;
    const int eh = tid >> 7;
    const int v = blockIdx.x * 128 + vl;
    float acc[B_];
#pragma unroll
    for (int b = 0; b < B_; ++b) acc[b] = 0.f;
    const float4* wrow = reinterpret_cast<const float4*>(Wm + (size_t)v * E_ + eh * 128);
#pragma unroll
    for (int c = 0; c < 4; ++c) {
        float4 wb[8];
#pragma unroll
        for (int j = 0; j < 8; ++j) wb[j] = wrow[c * 8 + j];
#pragma unroll
        for (int j = 0; j < 8; ++j) {
            const int e4 = eh * 128 + (c * 8 + j) * 4;
#pragma unroll
            for (int b = 0; b < B_; ++b) {
                const float4 uu = *reinterpret_cast<const float4*>(u_sh + b * E_ + e4);
                acc[b] += wb[j].x * uu.x + wb[j].y * uu.y + wb[j].z * uu.z + wb[j].w * uu.w;
            }
        }
    }
    if (eh == 1) {
#pragma unroll
        for (int b = 0; b < B_; ++b) part[vl * 33 + b] = acc[b];
    }
    __syncthreads();
    if (eh == 0) {
        float wx[B_];
        const float bv = bias[v];
        float mean = 0.f;
#pragma unroll
        for (int b = 0; b < B_; ++b) {
            wx[b] = acc[b] + part[vl * 33 + b] + bv;
            mean += wx[b];
        }
        mean *= (1.0f / B_);
        float var = 0.f;
#pragma unroll
        for (int b = 0; b < B_; ++b) {
            const float d = wx[b] - mean;
            var += d * d;
        }
        var *= (1.0f / B_);
        const float rstd = rsqrtf(var + 1e-5f);
        const float g = gamma[v], be = beta[v];
#pragma unroll
        for (int b = 0; b < B_; ++b) {
            const float y = g * (wx[b] - mean) * rstd + be;
            z[(size_t)b * V_ + v] = y + logf(VM[(size_t)b * V_ + v] + 1e-13f);
        }
    }
}

// ---------------- Kernel 4: partial sum of exp(z) per (b, chunk). 8 chunks per row.
// Safe without max-subtraction: |LN out| <= sqrt(B)*|gamma|+|beta| ~ 5.7 -> exp <= ~300.
__global__ __launch_bounds__(256) void k_lsep(const float* __restrict__ z,
                                              float* __restrict__ partial) {
    const int b = blockIdx.x >> 3;
    const int k = blockIdx.x & 7;
    const int tid = threadIdx.x;
    const float4* zr = reinterpret_cast<const float4*>(z + (size_t)b * V_ + k * 4000);
    float s = 0.f;
    for (int i = tid; i < 1000; i += 256) {
        const float4 x = zr[i];
        s += expf(x.x) + expf(x.y) + expf(x.z) + expf(x.w);
    }
#pragma unroll
    for (int off = 32; off > 0; off >>= 1)
        s += __shfl_xor(s, off, 64);
    __shared__ float ss[4];
    const int wave = tid >> 6, lane = tid & 63;
    if (lane == 0) ss[wave] = s;
    __syncthreads();
    if (tid == 0) partial[blockIdx.x] = ss[0] + ss[1] + ss[2] + ss[3];
}

// ---------------- Kernel 5: out = z - log(sum partials)
__global__ __launch_bounds__(256) void k_final(const float* __restrict__ z,
                                               const float* __restrict__ partial,
                                               float* __restrict__ out) {
    const int idx = blockIdx.x * 256 + threadIdx.x;  // 0..255999, one float4 each
    const int b = idx / (V_ / 4);
    const int v4 = idx % (V_ / 4);
    float s = 0.f;
#pragma unroll
    for (int k = 0; k < 8; ++k) s += partial[b * 8 + k];
    const float lse = logf(s);
    const float4 x = reinterpret_cast<const float4*>(z + (size_t)b * V_)[v4];
    float4 o;
    o.x = x.x - lse; o.y = x.y - lse; o.z = x.z - lse; o.w = x.w - lse;
    reinterpret_cast<float4*>(out + (size_t)b * V_)[v4] = o;
}

extern "C" void kernel_launch(void* const* d_in, const int* in_sizes, int n_in,
                              void* d_out, int out_size, void* d_ws, size_t ws_size,
                              hipStream_t stream) {
    const int* trainS = (const int*)d_in[0];
    const int* trainQ = (const int*)d_in[1];
    const float* trainVM = (const float*)d_in[2];
    const float* trainPM = (const float*)d_in[3];
    // d_in[4] = trainSM (unused by the forward pass)
    const float* trainQM = (const float*)d_in[5];
    const float* A1 = (const float*)d_in[6];
    const float* A2 = (const float*)d_in[7];
    const float* A3 = (const float*)d_in[8];
    const float* A4 = (const float*)d_in[9];
    const float* Wm = (const float*)d_in[10];
    const float* bias = (const float*)d_in[11];
    const float* gamma = (const float*)d_in[12];
    const float* beta = (const float*)d_in[13];
    float* out = (float*)d_out;

    float* ws = (float*)d_ws;
    float* u = ws;                                   // B*E = 8192
    float* embA = ws + 8192;                         // 4*B*M*E = 3,276,800
    float* z = embA + 4 * (B_ * M_ * E_);            // B*V = 1,024,000
    float* partial = z + (size_t)B_ * V_;            // 256

    k_embed<<<B_ * M_, 256, 0, stream>>>(trainS, A1, A2, A3, A4, embA);
    k_hops<<<B_, 1024, 0, stream>>>(trainQ, trainQM, A1, embA, trainPM, u);
    k_output<<<V_ / 128, 256, 0, stream>>>(u, Wm, bias, gamma, beta, trainVM, z);
    k_lsep<<<B_ * 8, 256, 0, stream>>>(z, partial);
    k_final<<<(B_ * V_ / 4) / 256, 256, 0, stream>>>(z, partial, out);
}